// Round 4
// baseline (415.452 us; speedup 1.0000x reference)
//
#include <hip/hip_runtime.h>
#include <cstdint>
#include <cstddef>

#define NN 4096
#define CC 256
#define GG 50

#define O_OUT1 819200
#define O_OUT2 1638400
#define O_OUT3 68747264
#define O_OUT4 68763648

typedef _Float16 half8 __attribute__((ext_vector_type(8)));
typedef float f32x4 __attribute__((ext_vector_type(4)));
typedef short short8 __attribute__((ext_vector_type(8)));

__device__ __forceinline__ unsigned bf16b(float f) {
    unsigned u = __float_as_uint(f);
    return (u + 0x7FFFu + ((u >> 16) & 1u)) >> 16;   // RNE f32->bf16
}
__device__ __forceinline__ float bf16f(short s) {
    return __uint_as_float(((unsigned)(unsigned short)s) << 16);
}

// ------------- k_proj v2: fp16 MFMA for the 3 projections (operand-swapped: D[j][pt]) ------
// 256 blocks x 256 thr (4 waves). Block owns 64 points; wave wv owns j-frags wv*6..wv*6+5.
// No LDS / no barriers in main loop. Epilogue: sim->bf16 fsim + rnorm, sem->LDS->seg MFMA
// ->in-register softmax, conf dot -> sigmoid.
__global__ __launch_bounds__(256) void k_proj(
    const float* __restrict__ x,
    const float* __restrict__ Wsem, const float* __restrict__ bsem,
    const float* __restrict__ Wseg, const float* __restrict__ bseg,
    const float* __restrict__ Wsim, const float* __restrict__ bsim,
    const float* __restrict__ Wconf, const float* __restrict__ bconf,
    const float* __restrict__ Wcl, const float* __restrict__ bcl,
    unsigned* __restrict__ fsimu, float* __restrict__ rnorm,
    float* __restrict__ out0, float* __restrict__ out1,
    float* __restrict__ out3, float* __restrict__ out4)
{
    __shared__ float hsem[64 * 132];       // Fsem staging [pt][d], stride 132
    __shared__ float confl[64], rns[64];

    int t = threadIdx.x;
    int lane = t & 63, wv = t >> 6;
    int rowl = lane & 15, quad = lane >> 4;
    int pbase = blockIdx.x * 64;

    if (t < 64) { confl[t] = 0.f; rns[t] = 0.f; }

    // A-operand: W^T — lane(rowl,quad) covers A[j = jfg*16+rowl][c = kc*32+quad*8+e]
    const float* wcol[6];
    #pragma unroll
    for (int jf = 0; jf < 6; ++jf) {
        int j384 = (wv * 6 + jf) * 16 + rowl;
        const float* m = (j384 < 128) ? Wsim : (j384 < 256) ? Wsem : Wconf;
        wcol[jf] = m + (j384 & 127);
    }
    // B-operand: x — lane(rowl,quad) covers B[c][pt = pf*16+rowl]
    const float* xrow[4];
    #pragma unroll
    for (int pf = 0; pf < 4; ++pf)
        xrow[pf] = x + (size_t)(pbase + pf * 16 + rowl) * CC;

    f32x4 acc[6][4];
    #pragma unroll
    for (int jf = 0; jf < 6; ++jf)
        #pragma unroll
        for (int pf = 0; pf < 4; ++pf) { f32x4 z = {0.f,0.f,0.f,0.f}; acc[jf][pf] = z; }

    #pragma unroll 2
    for (int kc = 0; kc < 8; ++kc) {
        half8 A[6];
        #pragma unroll
        for (int jf = 0; jf < 6; ++jf) {
            const float* wp = wcol[jf] + (size_t)(kc * 32 + quad * 8) * 128;
            #pragma unroll
            for (int e = 0; e < 8; ++e) A[jf][e] = (_Float16)wp[(size_t)e * 128];
        }
        half8 Bv[4];
        #pragma unroll
        for (int pf = 0; pf < 4; ++pf) {
            const float* xp = xrow[pf] + kc * 32 + quad * 8;
            float4 x0 = *(const float4*)xp;
            float4 x1 = *(const float4*)(xp + 4);
            Bv[pf][0] = (_Float16)x0.x; Bv[pf][1] = (_Float16)x0.y;
            Bv[pf][2] = (_Float16)x0.z; Bv[pf][3] = (_Float16)x0.w;
            Bv[pf][4] = (_Float16)x1.x; Bv[pf][5] = (_Float16)x1.y;
            Bv[pf][6] = (_Float16)x1.z; Bv[pf][7] = (_Float16)x1.w;
        }
        #pragma unroll
        for (int pf = 0; pf < 4; ++pf)
            #pragma unroll
            for (int jf = 0; jf < 6; ++jf)
                acc[jf][pf] = __builtin_amdgcn_mfma_f32_16x16x32_f16(A[jf], Bv[pf], acc[jf][pf], 0, 0, 0);
    }

    __syncthreads();   // confl/rns init visible to all; hsem region free

    // ---- epilogue part 1: distribute D[j][pt] (j = jfg*16 + quad*4 + e, pt = pf*16 + rowl) ----
    float rsum[4] = {0.f,0.f,0.f,0.f};
    float csum[4] = {0.f,0.f,0.f,0.f};
    bool hasSim = (wv * 6 < 8);            // waves 0,1
    bool hasConf = (wv * 6 + 5 >= 16);     // waves 2,3

    #pragma unroll
    for (int jf = 0; jf < 6; ++jf) {
        int jfg = wv * 6 + jf;
        int j0 = jfg * 16 + quad * 4;
        const float* barr = (j0 < 128) ? (bsim + j0)
                          : (j0 < 256) ? (bsem + (j0 - 128)) : (bconf + (j0 - 256));
        float4 b4 = *(const float4*)barr;
        if (jfg < 8) {                                  // ---- sim -> bf16 fsim + rnorm ----
            #pragma unroll
            for (int pf = 0; pf < 4; ++pf) {
                int pt = pf * 16 + rowl;
                f32x4 v = acc[jf][pf];
                unsigned p0 = bf16b(v[0] + b4.x) | (bf16b(v[1] + b4.y) << 16);
                unsigned p1 = bf16b(v[2] + b4.z) | (bf16b(v[3] + b4.w) << 16);
                *(uint2*)&fsimu[(size_t)(pbase + pt) * 64 + jfg * 8 + quad * 2] = make_uint2(p0, p1);
                float f0 = bf16f((short)(p0 & 0xFFFF)), f1 = bf16f((short)(p0 >> 16));
                float f2 = bf16f((short)(p1 & 0xFFFF)), f3 = bf16f((short)(p1 >> 16));
                rsum[pf] += f0*f0 + f1*f1 + f2*f2 + f3*f3;
            }
        } else if (jfg < 16) {                          // ---- sem -> LDS ----
            #pragma unroll
            for (int pf = 0; pf < 4; ++pf) {
                int pt = pf * 16 + rowl;
                f32x4 v = acc[jf][pf];
                f32x4 o;
                o[0] = v[0] + b4.x; o[1] = v[1] + b4.y; o[2] = v[2] + b4.z; o[3] = v[3] + b4.w;
                *(f32x4*)&hsem[pt * 132 + (jfg - 8) * 16 + quad * 4] = o;
            }
        } else {                                        // ---- conf partial dot ----
            float4 w4 = *(const float4*)&Wcl[(jfg - 16) * 16 + quad * 4];
            #pragma unroll
            for (int pf = 0; pf < 4; ++pf) {
                f32x4 v = acc[jf][pf];
                csum[pf] += (v[0] + b4.x) * w4.x + (v[1] + b4.y) * w4.y
                          + (v[2] + b4.z) * w4.z + (v[3] + b4.w) * w4.w;
            }
        }
    }
    if (hasSim) {
        #pragma unroll
        for (int pf = 0; pf < 4; ++pf) atomicAdd(&rns[pf * 16 + rowl], rsum[pf]);
    }
    if (hasConf) {
        #pragma unroll
        for (int pf = 0; pf < 4; ++pf) atomicAdd(&confl[pf * 16 + rowl], csum[pf]);
    }
    __syncthreads();

    // ---- conf sigmoid + rnorm writeback ----
    if (t < 64) {
        float cl = confl[t] + bcl[0];
        out4[pbase + t] = cl;
        out3[pbase + t] = 1.f / (1.f + __expf(-cl));
        rnorm[pbase + t] = rns[t];
    }

    // ---- seg logits via MFMA: D[g][pt] = Wseg^T (g x 128) @ Fsem^T (128 x pt) ----
    // wave wv handles pts wv*16 .. wv*16+15
    half8 As[4][4];
    #pragma unroll
    for (int gf = 0; gf < 4; ++gf) {
        int gg = gf * 16 + rowl;
        #pragma unroll
        for (int k2 = 0; k2 < 4; ++k2)
            #pragma unroll
            for (int e = 0; e < 8; ++e) {
                int d = k2 * 32 + quad * 8 + e;
                As[gf][k2][e] = (gg < GG) ? (_Float16)Wseg[(size_t)d * GG + gg] : (_Float16)0.f;
            }
    }
    f32x4 sacc[4];
    #pragma unroll
    for (int gf = 0; gf < 4; ++gf) { f32x4 z = {0.f,0.f,0.f,0.f}; sacc[gf] = z; }
    #pragma unroll
    for (int k2 = 0; k2 < 4; ++k2) {
        const float* hp = &hsem[(wv * 16 + rowl) * 132 + k2 * 32 + quad * 8];
        half8 Bh;
        #pragma unroll
        for (int e = 0; e < 8; ++e) Bh[e] = (_Float16)hp[e];
        #pragma unroll
        for (int gf = 0; gf < 4; ++gf)
            sacc[gf] = __builtin_amdgcn_mfma_f32_16x16x32_f16(As[gf][k2], Bh, sacc[gf], 0, 0, 0);
    }

    // per-pt softmax across the 4 quad-lanes holding this pt's g values
    float l[4][4];
    float mx = -1e30f;
    #pragma unroll
    for (int gf = 0; gf < 4; ++gf)
        #pragma unroll
        for (int e = 0; e < 4; ++e) {
            int g = gf * 16 + quad * 4 + e;
            float lv = (g < GG) ? sacc[gf][e] + bseg[g] : -1e30f;
            l[gf][e] = lv;
            mx = fmaxf(mx, lv);
        }
    mx = fmaxf(mx, __shfl_xor(mx, 16));
    mx = fmaxf(mx, __shfl_xor(mx, 32));
    float s = 0.f;
    #pragma unroll
    for (int gf = 0; gf < 4; ++gf)
        #pragma unroll
        for (int e = 0; e < 4; ++e) {
            int g = gf * 16 + quad * 4 + e;
            if (g < GG) s += __expf(l[gf][e] - mx);
        }
    s += __shfl_xor(s, 16);
    s += __shfl_xor(s, 32);
    float inv = 1.f / s;

    size_t orow = (size_t)(pbase + wv * 16 + rowl) * GG;
    #pragma unroll
    for (int gf = 0; gf < 4; ++gf)
        #pragma unroll
        for (int e = 0; e < 4; ++e) {
            int g = gf * 16 + quad * 4 + e;
            if (g < GG) {
                out1[orow + g] = l[gf][e];
                out0[orow + g] = __expf(l[gf][e] - mx) * inv;
            }
        }
}

// ------------- k_simmat v3: out2 = relu(10*(r_i - 2*F F^T + r_j)) --------------------------
// Store-bandwidth-oriented: block = 16 rows x 4096 cols, swept in 512-col chunks.
// Results go through LDS so every global store instruction writes 1 KB fully contiguous
// (fill-like pattern). A-frags register-resident across the whole block.
__global__ __launch_bounds__(256) void k_simmat(
    const short* __restrict__ fs, const float* __restrict__ rn, float* __restrict__ out2)
{
    __shared__ float tile[16 * 516];        // 16 rows x 512 cols, stride 516 (2-way = free)

    int t = threadIdx.x;
    int lane = t & 63, wv = t >> 6;
    int rowl = lane & 15, quad = lane >> 4;
    int b = blockIdx.y;
    int I = blockIdx.x * 16;

    const short8* F = (const short8*)(fs + (size_t)b * NN * 128);  // row = 16 short8
    const float* rb = rn + b * NN;
    float* ob = out2 + (size_t)b * NN * NN;

    // A-fragments for rows I..I+15 (lane holds row I+rowl, d = s*32 + quad*8 + e)
    short8 av[4];
    #pragma unroll
    for (int s = 0; s < 4; ++s)
        av[s] = F[(size_t)(I + rowl) * 16 + s * 4 + quad];

    f32x4 rI = *(const f32x4*)&rb[I + quad * 4];   // norms for rows I+quad*4+e

    for (int cb = 0; cb < NN; cb += 512) {
        int c0 = cb + wv * 128;                    // this wave's 128-col slice

        f32x4 acc[8];
        #pragma unroll
        for (int c = 0; c < 8; ++c) { f32x4 z = {0.f,0.f,0.f,0.f}; acc[c] = z; }

        #pragma unroll
        for (int s = 0; s < 4; ++s) {
            short8 bv[8];
            #pragma unroll
            for (int c = 0; c < 8; ++c)
                bv[c] = F[(size_t)(c0 + c * 16 + rowl) * 16 + s * 4 + quad];
            #pragma unroll
            for (int c = 0; c < 8; ++c)
                acc[c] = __builtin_amdgcn_mfma_f32_16x16x32_bf16(av[s], bv[c], acc[c], 0, 0, 0);
        }

        // epilogue: relu(10*(r_row + r_col) - 20*gram) -> LDS [row][col]
        #pragma unroll
        for (int c = 0; c < 8; ++c) {
            float rj = rb[c0 + c * 16 + rowl];
            f32x4 v = acc[c];
            int coff = wv * 128 + c * 16 + rowl;
            #pragma unroll
            for (int e = 0; e < 4; ++e) {
                float dv = fmaxf(10.f * (rI[e] + rj) - 20.f * v[e], 0.f);
                tile[(quad * 4 + e) * 516 + coff] = dv;
            }
        }
        __syncthreads();

        // cooperative store: wave wv stores rows wv*4..wv*4+3; 1 KB contiguous per instr
        #pragma unroll
        for (int rr = 0; rr < 4; ++rr) {
            int row = wv * 4 + rr;
            const f32x4* lp = (const f32x4*)&tile[row * 516];
            f32x4 v0 = lp[lane];
            f32x4 v1 = lp[64 + lane];
            size_t go = (size_t)(I + row) * NN + cb;
            __builtin_nontemporal_store(v0, (f32x4*)&ob[go + lane * 4]);
            __builtin_nontemporal_store(v1, (f32x4*)&ob[go + 256 + lane * 4]);
        }
        __syncthreads();
    }
}

extern "C" void kernel_launch(void* const* d_in, const int* in_sizes, int n_in,
                              void* d_out, int out_size, void* d_ws, size_t ws_size,
                              hipStream_t stream)
{
    const float* x     = (const float*)d_in[0];
    const float* Wsem  = (const float*)d_in[1];
    const float* bsem  = (const float*)d_in[2];
    const float* Wseg  = (const float*)d_in[3];
    const float* bseg  = (const float*)d_in[4];
    const float* Wsim  = (const float*)d_in[5];
    const float* bsim  = (const float*)d_in[6];
    const float* Wconf = (const float*)d_in[7];
    const float* bconf = (const float*)d_in[8];
    const float* Wcl   = (const float*)d_in[9];
    const float* bcl   = (const float*)d_in[10];

    // scratch: Fsim bf16 (4 MiB) + row norms fp32 (64 KiB)
    const size_t FSIM_BYTES = (size_t)4 * NN * 128 * 2;
    if (ws_size < FSIM_BYTES + (size_t)4 * NN * sizeof(float)) return;
    unsigned* fsim = (unsigned*)d_ws;
    float* rnorm = (float*)((char*)d_ws + FSIM_BYTES);

    float* out  = (float*)d_out;
    float* out0 = out;
    float* out1 = out + O_OUT1;
    float* out2 = out + O_OUT2;
    float* out3 = out + O_OUT3;
    float* out4 = out + O_OUT4;

    hipLaunchKernelGGL(k_proj, dim3(256), dim3(256), 0, stream,
                       x, Wsem, bsem, Wseg, bseg, Wsim, bsim, Wconf, bconf, Wcl, bcl,
                       fsim, rnorm, out0, out1, out3, out4);
    hipLaunchKernelGGL(k_simmat, dim3(256, 4), dim3(256), 0, stream,
                       (const short*)fsim, rnorm, out2);
}

// Round 6
// 356.519 us; speedup vs baseline: 1.1653x; 1.1653x over previous
//
#include <hip/hip_runtime.h>
#include <cstdint>
#include <cstddef>

#define NN 4096
#define CC 256
#define GG 50

#define O_OUT1 819200
#define O_OUT2 1638400
#define O_OUT3 68747264
#define O_OUT4 68763648

typedef _Float16 half8 __attribute__((ext_vector_type(8)));
typedef float f32x4 __attribute__((ext_vector_type(4)));
typedef short short8 __attribute__((ext_vector_type(8)));

__device__ __forceinline__ unsigned bf16b(float f) {
    unsigned u = __float_as_uint(f);
    return (u + 0x7FFFu + ((u >> 16) & 1u)) >> 16;   // RNE f32->bf16
}
__device__ __forceinline__ float bf16f(short s) {
    return __uint_as_float(((unsigned)(unsigned short)s) << 16);
}

// ------------- k_proj v2: fp16 MFMA for the 3 projections (operand-swapped: D[j][pt]) ------
// 256 blocks x 256 thr (4 waves). Block owns 64 points; wave wv owns j-frags wv*6..wv*6+5.
// No LDS / no barriers in main loop. Epilogue: sim->bf16 fsim + rnorm, sem->LDS->seg MFMA
// ->in-register softmax, conf dot -> sigmoid.
__global__ __launch_bounds__(256) void k_proj(
    const float* __restrict__ x,
    const float* __restrict__ Wsem, const float* __restrict__ bsem,
    const float* __restrict__ Wseg, const float* __restrict__ bseg,
    const float* __restrict__ Wsim, const float* __restrict__ bsim,
    const float* __restrict__ Wconf, const float* __restrict__ bconf,
    const float* __restrict__ Wcl, const float* __restrict__ bcl,
    unsigned* __restrict__ fsimu, float* __restrict__ rnorm,
    float* __restrict__ out0, float* __restrict__ out1,
    float* __restrict__ out3, float* __restrict__ out4)
{
    __shared__ float hsem[64 * 132];       // Fsem staging [pt][d], stride 132
    __shared__ float confl[64], rns[64];

    int t = threadIdx.x;
    int lane = t & 63, wv = t >> 6;
    int rowl = lane & 15, quad = lane >> 4;
    int pbase = blockIdx.x * 64;

    if (t < 64) { confl[t] = 0.f; rns[t] = 0.f; }

    // A-operand: W^T — lane(rowl,quad) covers A[j = jfg*16+rowl][c = kc*32+quad*8+e]
    const float* wcol[6];
    #pragma unroll
    for (int jf = 0; jf < 6; ++jf) {
        int j384 = (wv * 6 + jf) * 16 + rowl;
        const float* m = (j384 < 128) ? Wsim : (j384 < 256) ? Wsem : Wconf;
        wcol[jf] = m + (j384 & 127);
    }
    // B-operand: x — lane(rowl,quad) covers B[c][pt = pf*16+rowl]
    const float* xrow[4];
    #pragma unroll
    for (int pf = 0; pf < 4; ++pf)
        xrow[pf] = x + (size_t)(pbase + pf * 16 + rowl) * CC;

    f32x4 acc[6][4];
    #pragma unroll
    for (int jf = 0; jf < 6; ++jf)
        #pragma unroll
        for (int pf = 0; pf < 4; ++pf) { f32x4 z = {0.f,0.f,0.f,0.f}; acc[jf][pf] = z; }

    #pragma unroll 2
    for (int kc = 0; kc < 8; ++kc) {
        half8 A[6];
        #pragma unroll
        for (int jf = 0; jf < 6; ++jf) {
            const float* wp = wcol[jf] + (size_t)(kc * 32 + quad * 8) * 128;
            #pragma unroll
            for (int e = 0; e < 8; ++e) A[jf][e] = (_Float16)wp[(size_t)e * 128];
        }
        half8 Bv[4];
        #pragma unroll
        for (int pf = 0; pf < 4; ++pf) {
            const float* xp = xrow[pf] + kc * 32 + quad * 8;
            float4 x0 = *(const float4*)xp;
            float4 x1 = *(const float4*)(xp + 4);
            Bv[pf][0] = (_Float16)x0.x; Bv[pf][1] = (_Float16)x0.y;
            Bv[pf][2] = (_Float16)x0.z; Bv[pf][3] = (_Float16)x0.w;
            Bv[pf][4] = (_Float16)x1.x; Bv[pf][5] = (_Float16)x1.y;
            Bv[pf][6] = (_Float16)x1.z; Bv[pf][7] = (_Float16)x1.w;
        }
        #pragma unroll
        for (int pf = 0; pf < 4; ++pf)
            #pragma unroll
            for (int jf = 0; jf < 6; ++jf)
                acc[jf][pf] = __builtin_amdgcn_mfma_f32_16x16x32_f16(A[jf], Bv[pf], acc[jf][pf], 0, 0, 0);
    }

    __syncthreads();   // confl/rns init visible to all; hsem region free

    // ---- epilogue part 1: distribute D[j][pt] (j = jfg*16 + quad*4 + e, pt = pf*16 + rowl) ----
    float rsum[4] = {0.f,0.f,0.f,0.f};
    float csum[4] = {0.f,0.f,0.f,0.f};
    bool hasSim = (wv * 6 < 8);            // waves 0,1
    bool hasConf = (wv * 6 + 5 >= 16);     // waves 2,3

    #pragma unroll
    for (int jf = 0; jf < 6; ++jf) {
        int jfg = wv * 6 + jf;
        int j0 = jfg * 16 + quad * 4;
        const float* barr = (j0 < 128) ? (bsim + j0)
                          : (j0 < 256) ? (bsem + (j0 - 128)) : (bconf + (j0 - 256));
        float4 b4 = *(const float4*)barr;
        if (jfg < 8) {                                  // ---- sim -> bf16 fsim + rnorm ----
            #pragma unroll
            for (int pf = 0; pf < 4; ++pf) {
                int pt = pf * 16 + rowl;
                f32x4 v = acc[jf][pf];
                unsigned p0 = bf16b(v[0] + b4.x) | (bf16b(v[1] + b4.y) << 16);
                unsigned p1 = bf16b(v[2] + b4.z) | (bf16b(v[3] + b4.w) << 16);
                *(uint2*)&fsimu[(size_t)(pbase + pt) * 64 + jfg * 8 + quad * 2] = make_uint2(p0, p1);
                float f0 = bf16f((short)(p0 & 0xFFFF)), f1 = bf16f((short)(p0 >> 16));
                float f2 = bf16f((short)(p1 & 0xFFFF)), f3 = bf16f((short)(p1 >> 16));
                rsum[pf] += f0*f0 + f1*f1 + f2*f2 + f3*f3;
            }
        } else if (jfg < 16) {                          // ---- sem -> LDS ----
            #pragma unroll
            for (int pf = 0; pf < 4; ++pf) {
                int pt = pf * 16 + rowl;
                f32x4 v = acc[jf][pf];
                f32x4 o;
                o[0] = v[0] + b4.x; o[1] = v[1] + b4.y; o[2] = v[2] + b4.z; o[3] = v[3] + b4.w;
                *(f32x4*)&hsem[pt * 132 + (jfg - 8) * 16 + quad * 4] = o;
            }
        } else {                                        // ---- conf partial dot ----
            float4 w4 = *(const float4*)&Wcl[(jfg - 16) * 16 + quad * 4];
            #pragma unroll
            for (int pf = 0; pf < 4; ++pf) {
                f32x4 v = acc[jf][pf];
                csum[pf] += (v[0] + b4.x) * w4.x + (v[1] + b4.y) * w4.y
                          + (v[2] + b4.z) * w4.z + (v[3] + b4.w) * w4.w;
            }
        }
    }
    if (hasSim) {
        #pragma unroll
        for (int pf = 0; pf < 4; ++pf) atomicAdd(&rns[pf * 16 + rowl], rsum[pf]);
    }
    if (hasConf) {
        #pragma unroll
        for (int pf = 0; pf < 4; ++pf) atomicAdd(&confl[pf * 16 + rowl], csum[pf]);
    }
    __syncthreads();

    // ---- conf sigmoid + rnorm writeback ----
    if (t < 64) {
        float cl = confl[t] + bcl[0];
        out4[pbase + t] = cl;
        out3[pbase + t] = 1.f / (1.f + __expf(-cl));
        rnorm[pbase + t] = rns[t];
    }

    // ---- seg logits via MFMA: D[g][pt] = Wseg^T (g x 128) @ Fsem^T (128 x pt) ----
    // wave wv handles pts wv*16 .. wv*16+15
    half8 As[4][4];
    #pragma unroll
    for (int gf = 0; gf < 4; ++gf) {
        int gg = gf * 16 + rowl;
        #pragma unroll
        for (int k2 = 0; k2 < 4; ++k2)
            #pragma unroll
            for (int e = 0; e < 8; ++e) {
                int d = k2 * 32 + quad * 8 + e;
                As[gf][k2][e] = (gg < GG) ? (_Float16)Wseg[(size_t)d * GG + gg] : (_Float16)0.f;
            }
    }
    f32x4 sacc[4];
    #pragma unroll
    for (int gf = 0; gf < 4; ++gf) { f32x4 z = {0.f,0.f,0.f,0.f}; sacc[gf] = z; }
    #pragma unroll
    for (int k2 = 0; k2 < 4; ++k2) {
        const float* hp = &hsem[(wv * 16 + rowl) * 132 + k2 * 32 + quad * 8];
        half8 Bh;
        #pragma unroll
        for (int e = 0; e < 8; ++e) Bh[e] = (_Float16)hp[e];
        #pragma unroll
        for (int gf = 0; gf < 4; ++gf)
            sacc[gf] = __builtin_amdgcn_mfma_f32_16x16x32_f16(As[gf][k2], Bh, sacc[gf], 0, 0, 0);
    }

    // per-pt softmax across the 4 quad-lanes holding this pt's g values
    float l[4][4];
    float mx = -1e30f;
    #pragma unroll
    for (int gf = 0; gf < 4; ++gf)
        #pragma unroll
        for (int e = 0; e < 4; ++e) {
            int g = gf * 16 + quad * 4 + e;
            float lv = (g < GG) ? sacc[gf][e] + bseg[g] : -1e30f;
            l[gf][e] = lv;
            mx = fmaxf(mx, lv);
        }
    mx = fmaxf(mx, __shfl_xor(mx, 16));
    mx = fmaxf(mx, __shfl_xor(mx, 32));
    float s = 0.f;
    #pragma unroll
    for (int gf = 0; gf < 4; ++gf)
        #pragma unroll
        for (int e = 0; e < 4; ++e) {
            int g = gf * 16 + quad * 4 + e;
            if (g < GG) s += __expf(l[gf][e] - mx);
        }
    s += __shfl_xor(s, 16);
    s += __shfl_xor(s, 32);
    float inv = 1.f / s;

    size_t orow = (size_t)(pbase + wv * 16 + rowl) * GG;
    #pragma unroll
    for (int gf = 0; gf < 4; ++gf)
        #pragma unroll
        for (int e = 0; e < 4; ++e) {
            int g = gf * 16 + quad * 4 + e;
            if (g < GG) {
                out1[orow + g] = l[gf][e];
                out0[orow + g] = __expf(l[gf][e] - mx) * inv;
            }
        }
}

// ------------- k_simmat: out2 = relu(10*(r_i - 2*F F^T + r_j)) -----------------------------
// symmetric: only upper-triangle tile pairs launched; each block writes tile (I,J) with
// scalar stores and tile (J,I) with f32x4 stores (fragment rows -> mirrored contiguous cols)
__global__ __launch_bounds__(256) void k_simmat(
    const short* __restrict__ fs, const float* __restrict__ rn, float* __restrict__ out2)
{
    int t = threadIdx.x;
    int lane = t & 63, wv = t >> 6;
    int b = blockIdx.y;

    // decode upper-triangle pair: p = tj*(tj+1)/2 + ti, ti <= tj
    int p = blockIdx.x;
    int tj = (int)((sqrtf((float)(8 * p + 1)) - 1.f) * 0.5f);
    while ((tj + 1) * (tj + 2) / 2 <= p) ++tj;
    while (tj * (tj + 1) / 2 > p) --tj;
    int ti = p - tj * (tj + 1) / 2;

    int I = ti * 128 + (wv >> 1) * 64;
    int J = tj * 128 + (wv & 1) * 64;
    int rowl = lane & 15, quad = lane >> 4;

    const short8* F = (const short8*)(fs + (size_t)b * NN * 128);  // row = 16 short8
    const float* rb = rn + b * NN;

    f32x4 acc[4][4];
    #pragma unroll
    for (int r = 0; r < 4; ++r)
        #pragma unroll
        for (int c = 0; c < 4; ++c) { f32x4 z = {0.f,0.f,0.f,0.f}; acc[r][c] = z; }

    #pragma unroll
    for (int s = 0; s < 4; ++s) {
        short8 av[4], bv[4];
        #pragma unroll
        for (int r = 0; r < 4; ++r)
            av[r] = F[(size_t)(I + r * 16 + rowl) * 16 + s * 4 + quad];
        #pragma unroll
        for (int c = 0; c < 4; ++c)
            bv[c] = F[(size_t)(J + c * 16 + rowl) * 16 + s * 4 + quad];
        #pragma unroll
        for (int r = 0; r < 4; ++r)
            #pragma unroll
            for (int c = 0; c < 4; ++c)
                acc[r][c] = __builtin_amdgcn_mfma_f32_16x16x32_bf16(av[r], bv[c], acc[r][c], 0, 0, 0);
    }

    // precomputed norms: rI4[r][e] = r(I + r*16 + quad*4 + e), rJs[c] = r(J + c*16 + rowl)
    f32x4 rI4[4];
    float rJs[4];
    #pragma unroll
    for (int r = 0; r < 4; ++r)
        rI4[r] = *(const f32x4*)&rb[I + r * 16 + quad * 4];
    #pragma unroll
    for (int c = 0; c < 4; ++c)
        rJs[c] = rb[J + c * 16 + rowl];

    // relu'd D values in place
    #pragma unroll
    for (int r = 0; r < 4; ++r)
        #pragma unroll
        for (int c = 0; c < 4; ++c) {
            f32x4 v = acc[r][c];
            float rj = rJs[c];
            f32x4 o;
            #pragma unroll
            for (int e = 0; e < 4; ++e)
                o[e] = fmaxf(10.f * (rI4[r][e] + rj) - 20.f * v[e], 0.f);
            acc[r][c] = o;
        }

    float* ob = out2 + (size_t)b * NN * NN;

    // tile (I,J): row = I + r*16 + quad*4 + e, col = J + c*16 + rowl (scalar, NT)
    #pragma unroll
    for (int r = 0; r < 4; ++r) {
        int rbase = I + r * 16 + quad * 4;
        #pragma unroll
        for (int c = 0; c < 4; ++c) {
            int col = J + c * 16 + rowl;
            f32x4 v = acc[r][c];
            #pragma unroll
            for (int e = 0; e < 4; ++e)
                __builtin_nontemporal_store(v[e], &ob[(size_t)(rbase + e) * NN + col]);
        }
    }

    // tile (J,I) by symmetry: row = J + c*16 + rowl, cols I + r*16 + quad*4 .. +3 (f32x4, NT)
    if (ti != tj) {
        #pragma unroll
        for (int c = 0; c < 4; ++c) {
            size_t rowoff = (size_t)(J + c * 16 + rowl) * NN;
            #pragma unroll
            for (int r = 0; r < 4; ++r)
                __builtin_nontemporal_store(acc[r][c],
                    (f32x4*)&ob[rowoff + (I + r * 16 + quad * 4)]);
        }
    }
}

extern "C" void kernel_launch(void* const* d_in, const int* in_sizes, int n_in,
                              void* d_out, int out_size, void* d_ws, size_t ws_size,
                              hipStream_t stream)
{
    const float* x     = (const float*)d_in[0];
    const float* Wsem  = (const float*)d_in[1];
    const float* bsem  = (const float*)d_in[2];
    const float* Wseg  = (const float*)d_in[3];
    const float* bseg  = (const float*)d_in[4];
    const float* Wsim  = (const float*)d_in[5];
    const float* bsim  = (const float*)d_in[6];
    const float* Wconf = (const float*)d_in[7];
    const float* bconf = (const float*)d_in[8];
    const float* Wcl   = (const float*)d_in[9];
    const float* bcl   = (const float*)d_in[10];

    // scratch: Fsim bf16 (4 MiB) + row norms fp32 (64 KiB)
    const size_t FSIM_BYTES = (size_t)4 * NN * 128 * 2;
    if (ws_size < FSIM_BYTES + (size_t)4 * NN * sizeof(float)) return;
    unsigned* fsim = (unsigned*)d_ws;
    float* rnorm = (float*)((char*)d_ws + FSIM_BYTES);

    float* out  = (float*)d_out;
    float* out0 = out;
    float* out1 = out + O_OUT1;
    float* out2 = out + O_OUT2;
    float* out3 = out + O_OUT3;
    float* out4 = out + O_OUT4;

    hipLaunchKernelGGL(k_proj, dim3(256), dim3(256), 0, stream,
                       x, Wsem, bsem, Wseg, bseg, Wsim, bsim, Wconf, bconf, Wcl, bcl,
                       fsim, rnorm, out0, out1, out3, out4);
    hipLaunchKernelGGL(k_simmat, dim3(528, 4, 1), dim3(256), 0, stream,
                       (const short*)fsim, rnorm, out2);
}